// Round 5
// baseline (417.230 us; speedup 1.0000x reference)
//
#include <hip/hip_runtime.h>
#include <stdint.h>

#define M_ROWS 4096
#define N_COLS 16384
#define K_HARD 163          // int(0.01 * (16384 - 1))
#define DELTA_W 5.0f
#define BLOCK  256
#define THRESH 2.0f
#define KEY_MIN 0xC0000000u // f2key(2.0f)
#define SEGG   192          // groups per (row,wave) segment; mean ~90, sd ~9
#define CAP    1536         // compacted candidate cap (mean 373, sd 19)
#define NB     1024         // histogram bins
#define SMALL  64           // pivot-bin resolve cap (expect ~2)
#define SLOTA  13           // 12 real slots + 1 trash slot (c==12 clobber guard)

__device__ __forceinline__ uint32_t f2key(float x) {
    uint32_t u = __float_as_uint(x);
    return u ^ (uint32_t)(((int32_t)u >> 31) | 0x80000000u);
}
__device__ __forceinline__ float key2f(uint32_t k) {
    uint32_t u = (k & 0x80000000u) ? (k & 0x7fffffffu) : ~k;
    return __uint_as_float(u);
}
__device__ __forceinline__ float softplus_f(float x) {
    return fmaxf(x, 0.0f) + log1pf(__expf(-fabsf(x)));
}

// fallback-only parallel pivot finder over NB ascending bins
__device__ void pivot_scan(const uint32_t* hist, int K,
                           int* part, int* pivot, int* krem) {
    const int t = threadIdx.x;
    const int bpt = NB / BLOCK;
    const int base = t * bpt;
    int mypart = 0;
    for (int i = 0; i < bpt; ++i) mypart += (int)hist[base + i];
    part[t] = mypart;
    __syncthreads();
    for (int off = 1; off < BLOCK; off <<= 1) {
        int v = part[t];
        if (t + off < BLOCK) v += part[t + off];
        __syncthreads();
        part[t] = v;
        __syncthreads();
    }
    const int above = part[t] - mypart;
    if (above < K && above + mypart >= K) {
        int running = above;
        for (int b = base + bpt - 1; b >= base; --b) {
            int c = (int)hist[b];
            if (running < K && running + c >= K) { *pivot = b; *krem = K - running; }
            running += c;
        }
    }
    __syncthreads();
}

// ---- K1: pure filter stream. No LDS, no barriers, no atomics. ----
__global__ __launch_bounds__(BLOCK) void k1_filter(
        const float* __restrict__ inputs,
        uint32_t* __restrict__ counts,
        float4* __restrict__ groups) {
    const int row = blockIdx.x;
    const int lane = threadIdx.x & 63;
    const int wid = threadIdx.x >> 6;
    const float4* rp4 = (const float4*)(inputs + (size_t)row * N_COLS);
    float4* seg = groups + (size_t)(row * 4 + wid) * SEGG;
    uint32_t wcount = 0;
#pragma unroll 4
    for (int it = 0; it < N_COLS / (BLOCK * 4); ++it) {
        const float4 v = rp4[wid * 1024 + it * 64 + lane];
        const float m = fmaxf(fmaxf(v.x, v.y), fmaxf(v.z, v.w));
        const bool pred = (m >= THRESH);
        const unsigned long long mask = __ballot(pred);
        if (pred) {
            const int below = __builtin_amdgcn_mbcnt_hi(
                (uint32_t)(mask >> 32),
                __builtin_amdgcn_mbcnt_lo((uint32_t)mask, 0));
            const uint32_t off = wcount + (uint32_t)below;
            if (off < SEGG) seg[off] = v;   // dense sequential 16B stream per wave
        }
        wcount += (uint32_t)__popcll(mask);
    }
    if (lane == 0) counts[row * 4 + wid] = wcount;
}

// ---- K2: per-row select from compacted groups ----
__global__ __launch_bounds__(BLOCK) void k2_select(
        const float* __restrict__ inputs,
        const int* __restrict__ targets,
        const uint32_t* __restrict__ counts,
        const float4* __restrict__ groups,
        float* __restrict__ out) {
    __shared__ float    s_slots_f[BLOCK * SLOTA];  // 13.3 KB; aliased as hist
    __shared__ uint32_t s_cand[CAP];               // 6 KB; aliased as part (fallback)
    __shared__ int s_wc[4], s_wt[4];
    __shared__ int s_found, s_pivot, s_krem, s_nsmall;
    __shared__ uint32_t s_skey[SMALL];
    __shared__ int s_sidx[SMALL];
    __shared__ float s_fw[4];

    const int row = blockIdx.x;
    const int t = threadIdx.x;
    const int lane = t & 63;
    const int wid = t >> 6;
    const float* rowp = inputs + (size_t)row * N_COLS;
    const int target = targets[row];

    if (t == 0) s_found = -1;
    if (t < 4) s_wc[t] = (int)counts[row * 4 + t];
    __syncthreads();
    const int cw0 = s_wc[0], cw1 = s_wc[1], cw2 = s_wc[2], cw3 = s_wc[3];
    const bool ovf = (cw0 > SEGG) | (cw1 > SEGG) | (cw2 > SEGG) | (cw3 > SEGG);

    // ---- scan my wave's segment, branchless 13-slot filter ----
    float* myslots = s_slots_f + t * SLOTA;
    uint32_t c = 0;
    if (!ovf) {
        const int cw = s_wc[wid];
        const float4* seg = groups + (size_t)(row * 4 + wid) * SEGG;
#pragma unroll
        for (int g = 0; g < SEGG / 64; ++g) {       // up to 3 groups/lane
            const int gi = g * 64 + lane;
            if (gi < cw) {
                const float4 v = seg[gi];
                myslots[min(c, (uint32_t)(SLOTA - 1))] = v.x; c += (v.x >= THRESH);
                myslots[min(c, (uint32_t)(SLOTA - 1))] = v.y; c += (v.y >= THRESH);
                myslots[min(c, (uint32_t)(SLOTA - 1))] = v.z; c += (v.z >= THRESH);
                myslots[min(c, (uint32_t)(SLOTA - 1))] = v.w; c += (v.w >= THRESH);
            }
        }
    }
    // c <= 12 deterministically (<= 3 groups * 4 elements)

    // ---- shfl scan -> compact keys into s_cand ----
    const int stored = (int)c;
    int inc = stored;
    for (int off = 1; off < 64; off <<= 1) {
        int y = __shfl_up(inc, off);
        if (lane >= off) inc += y;
    }
    if (lane == 63) s_wt[wid] = inc;
    __syncthreads();   // B1
    const int w0 = s_wt[0], w1 = s_wt[1], w2 = s_wt[2], w3 = s_wt[3];
    const int total = w0 + w1 + w2 + w3;
    const int wbase = (wid > 0 ? w0 : 0) + (wid > 1 ? w1 : 0) + (wid > 2 ? w2 : 0);
    const int myoff = wbase + inc - stored;
    for (int j = 0; j < stored; ++j) {
        const int d = myoff + j;
        if (d < CAP) s_cand[d] = f2key(myslots[j]);
    }
    __syncthreads();   // B2

    // ---- remove one instance of the positive ----
    const float pos = rowp[target];
    const uint32_t tkey = f2key(pos);
    const int tclamp = min(total, CAP);
    if (pos >= THRESH) {
        for (int i = t; i < tclamp; i += BLOCK)
            if (s_cand[i] == tkey) { atomicCAS(&s_found, -1, i); break; }
    }
    __syncthreads();   // B3
    int ncand = total;
    if (s_found >= 0) {
        ncand = total - 1;
        if (t == 0) s_cand[s_found] = s_cand[ncand];
    }
    __syncthreads();   // B4

    const bool fast = !ovf && (total <= CAP) && (ncand >= K_HARD);
    bool needfb = !fast;
    float local = 0.0f;
    uint32_t* hist = (uint32_t*)s_slots_f;   // alias: slot reads all done pre-B2

    if (fast) {
        for (int i = t; i < NB; i += BLOCK) hist[i] = 0;
        __syncthreads();   // B5
        for (int i = t; i < ncand; i += BLOCK)
            atomicAdd(&hist[min((s_cand[i] - KEY_MIN) >> 14, (uint32_t)(NB - 1))], 1u);
        __syncthreads();   // B6

        // shfl suffix scan to find pivot bin
        const int base4 = t * 4;
        const int c0 = (int)hist[base4], c1 = (int)hist[base4 + 1],
                  c2 = (int)hist[base4 + 2], c3 = (int)hist[base4 + 3];
        const int own = c0 + c1 + c2 + c3;
        int suf = own;
        for (int off = 1; off < 64; off <<= 1) {
            int y = __shfl_down(suf, off);
            if (lane + off < 64) suf += y;
        }
        if (lane == 0) s_wt[wid] = suf;
        if (t == 0) s_nsmall = 0;
        __syncthreads();   // B7
        int wsuf = 0;
        for (int w = wid + 1; w < 4; ++w) wsuf += s_wt[w];
        int run = wsuf + (suf - own);
        {
            const int cs[4] = {c0, c1, c2, c3};
            for (int b = 3; b >= 0; --b) {
                const int cc = cs[b];
                if (run < K_HARD && run + cc >= K_HARD) {
                    s_pivot = base4 + b; s_krem = K_HARD - run;
                }
                run += cc;
            }
        }
        __syncthreads();   // B8
        const uint32_t B = (uint32_t)s_pivot;
        const int krem = s_krem;

        for (int i = t; i < ncand; i += BLOCK) {
            const uint32_t k = s_cand[i];
            const uint32_t kb = min((k - KEY_MIN) >> 14, (uint32_t)(NB - 1));
            if (kb > B) local += softplus_f(key2f(k));
            else if (kb == B) {
                const int d = atomicAdd(&s_nsmall, 1);
                if (d < SMALL) { s_skey[d] = k; s_sidx[d] = i; }
            }
        }
        __syncthreads();   // B9
        const int m = s_nsmall;
        if (m > SMALL) { needfb = true; local = 0.0f; }
        else {
            for (int i = t; i < m; i += BLOCK) {
                const uint32_t ki = s_skey[i]; const int ii = s_sidx[i];
                int r = 0;
                for (int j = 0; j < m; ++j) {
                    const uint32_t kj = s_skey[j];
                    r += (kj > ki) || (kj == ki && s_sidx[j] < ii);
                }
                if (r < krem) local += softplus_f(key2f(ki));
            }
        }
    }

    if (needfb) {
        // ---- generic exact fallback: 10+10+10+2 radix from global ----
        local = 0.0f;
        int* part = (int*)s_cand;
        for (int i = t; i < NB; i += BLOCK) hist[i] = 0;
        __syncthreads();
        for (int j = t; j < N_COLS; j += BLOCK) {
            if (j == target) continue;
            atomicAdd(&hist[f2key(rowp[j]) >> 22], 1u);
        }
        __syncthreads();
        pivot_scan(hist, K_HARD, part, &s_pivot, &s_krem);
        const int p1 = s_pivot, k1r = s_krem;

        for (int i = t; i < NB; i += BLOCK) hist[i] = 0;
        __syncthreads();
        for (int j = t; j < N_COLS; j += BLOCK) {
            if (j == target) continue;
            const uint32_t k = f2key(rowp[j]);
            if ((int)(k >> 22) == p1) atomicAdd(&hist[(k >> 12) & 1023u], 1u);
        }
        __syncthreads();
        pivot_scan(hist, k1r, part, &s_pivot, &s_krem);
        const uint32_t pref2 = ((uint32_t)p1 << 10) | (uint32_t)s_pivot;
        const int k2r = s_krem;

        for (int i = t; i < NB; i += BLOCK) hist[i] = 0;
        __syncthreads();
        for (int j = t; j < N_COLS; j += BLOCK) {
            if (j == target) continue;
            const uint32_t k = f2key(rowp[j]);
            if ((k >> 12) == pref2) atomicAdd(&hist[(k >> 2) & 1023u], 1u);
        }
        __syncthreads();
        pivot_scan(hist, k2r, part, &s_pivot, &s_krem);
        const uint32_t pref3 = (pref2 << 10) | (uint32_t)s_pivot;
        const int k3r = s_krem;

        for (int i = t; i < 4; i += BLOCK) hist[i] = 0;
        __syncthreads();
        for (int j = t; j < N_COLS; j += BLOCK) {
            if (j == target) continue;
            const uint32_t k = f2key(rowp[j]);
            if ((k >> 2) == pref3) atomicAdd(&hist[k & 3u], 1u);
        }
        __syncthreads();
        if (t == 0) {
            int running = 0;
            for (int b = 3; b >= 0; --b) {
                const int cc = (int)hist[b];
                if (running < k3r && running + cc >= k3r) {
                    s_pivot = b; s_krem = k3r - running;
                }
                running += cc;
            }
        }
        __syncthreads();
        const uint32_t T = (pref3 << 2) | (uint32_t)s_pivot;
        const int tie = s_krem;

        for (int j = t; j < N_COLS; j += BLOCK) {
            if (j == target) continue;
            const uint32_t k = f2key(rowp[j]);
            if (k > T) local += softplus_f(key2f(k));
        }
        if (t == 0) local += (float)tie * softplus_f(key2f(T));
    }

    // ---- block reduce + epilogue ----
    for (int off = 32; off > 0; off >>= 1) local += __shfl_down(local, off);
    if (lane == 0) s_fw[wid] = local;
    __syncthreads();
    if (t == 0) {
        const float tot = s_fw[0] + s_fw[1] + s_fw[2] + s_fw[3];
        const float l_neg = tot / (float)K_HARD;
        const float l_pos = softplus_f(-pos);
        const float rowval = (DELTA_W * l_pos + l_neg) * (1.0f / (float)M_ROWS);
        atomicAdd(out, rowval);
    }
}

__global__ void mmcl_zero_out(float* out) { out[0] = 0.0f; }

extern "C" void kernel_launch(void* const* d_in, const int* in_sizes, int n_in,
                              void* d_out, int out_size, void* d_ws, size_t ws_size,
                              hipStream_t stream) {
    const float* inputs = (const float*)d_in[0];
    const int* targets = (const int*)d_in[1];
    float* out = (float*)d_out;
    uint32_t* counts = (uint32_t*)d_ws;                       // 64 KB
    float4* groups = (float4*)((char*)d_ws + 65536);          // ~50 MB
    mmcl_zero_out<<<1, 1, 0, stream>>>(out);
    k1_filter<<<M_ROWS, BLOCK, 0, stream>>>(inputs, counts, groups);
    k2_select<<<M_ROWS, BLOCK, 0, stream>>>(inputs, targets, counts, groups, out);
}

// Round 6
// 364.556 us; speedup vs baseline: 1.1445x; 1.1445x over previous
//
#include <hip/hip_runtime.h>
#include <stdint.h>

#define M_ROWS 4096
#define N_COLS 16384
#define K_HARD 163          // int(0.01 * (16384 - 1))
#define DELTA_W 5.0f
#define BLOCK  256
#define THRESH 2.0f
#define KEY_MIN 0xC0000000u // f2key(2.0f)
#define SEGG   192          // stored float4-groups per wave (mean ~90, sd ~9)
#define CAP    1536         // compacted candidate cap (mean 373, sd 19)
#define NB     1024         // histogram bins
#define SMALL  64           // pivot-bin resolve cap (expect ~2)

__device__ __forceinline__ uint32_t f2key(float x) {
    uint32_t u = __float_as_uint(x);
    return u ^ (uint32_t)(((int32_t)u >> 31) | 0x80000000u);
}
__device__ __forceinline__ float key2f(uint32_t k) {
    uint32_t u = (k & 0x80000000u) ? (k & 0x7fffffffu) : ~k;
    return __uint_as_float(u);
}
__device__ __forceinline__ float softplus_f(float x) {
    return fmaxf(x, 0.0f) + log1pf(__expf(-fabsf(x)));
}

// fallback-only parallel pivot finder over NB ascending bins
__device__ void pivot_scan(const uint32_t* hist, int K,
                           int* part, int* pivot, int* krem) {
    const int t = threadIdx.x;
    const int bpt = NB / BLOCK;
    const int base = t * bpt;
    int mypart = 0;
    for (int i = 0; i < bpt; ++i) mypart += (int)hist[base + i];
    part[t] = mypart;
    __syncthreads();
    for (int off = 1; off < BLOCK; off <<= 1) {
        int v = part[t];
        if (t + off < BLOCK) v += part[t + off];
        __syncthreads();
        part[t] = v;
        __syncthreads();
    }
    const int above = part[t] - mypart;
    if (above < K && above + mypart >= K) {
        int running = above;
        for (int b = base + bpt - 1; b >= base; --b) {
            int c = (int)hist[b];
            if (running < K && running + c >= K) { *pivot = b; *krem = K - running; }
            running += c;
        }
    }
    __syncthreads();
}

__global__ __launch_bounds__(BLOCK) void mmcl_main(
        const float* __restrict__ inputs,
        const int* __restrict__ targets,
        float* __restrict__ partial) {
    __shared__ float4   s_seg[4 * SEGG];   // 12 KB; aliased as hist after use
    __shared__ uint32_t s_cand[CAP];       // 6 KB; aliased as part[] in fallback
    __shared__ int s_wt[4], s_wc[4];
    __shared__ int s_found, s_pivot, s_krem, s_nsmall;
    __shared__ uint32_t s_skey[SMALL];
    __shared__ int s_sidx[SMALL];
    __shared__ float s_fw[4];

    const int row = blockIdx.x;
    const int t = threadIdx.x;
    const int lane = t & 63;
    const int wid = t >> 6;
    const float* rowp = inputs + (size_t)row * N_COLS;
    const int target = targets[row];

    if (t == 0) s_found = -1;

    // ---- stream: ballot-compact float4 groups into per-wave LDS segments ----
    float4* wseg = s_seg + wid * SEGG;
    uint32_t wcount = 0;
    const float4* rp4 = (const float4*)rowp;
#pragma unroll 4
    for (int it = 0; it < 16; ++it) {
        const float4 v = rp4[wid * 1024 + it * 64 + lane];
        const float m = fmaxf(fmaxf(v.x, v.y), fmaxf(v.z, v.w));
        const bool pred = (m >= THRESH);
        const unsigned long long mask = __ballot(pred);
        if (pred) {
            const int below = __builtin_amdgcn_mbcnt_hi(
                (uint32_t)(mask >> 32),
                __builtin_amdgcn_mbcnt_lo((uint32_t)mask, 0));
            const uint32_t off = wcount + (uint32_t)below;
            if (off < SEGG) wseg[off] = v;
        }
        wcount += (uint32_t)__popcll(mask);
    }
    if (lane == 0) s_wc[wid] = (int)wcount;

    // ---- extraction count (own-wave LDS only; no barrier needed yet) ----
    const int cwg = (int)min(wcount, (uint32_t)SEGG);
    int cnt = 0;
#pragma unroll
    for (int g = 0; g < 3; ++g) {
        const int gi = g * 64 + lane;
        if (gi < cwg) {
            const float4 v = wseg[gi];
            cnt += (v.x >= THRESH) + (v.y >= THRESH) + (v.z >= THRESH) + (v.w >= THRESH);
        }
    }
    int inc = cnt;
    for (int off = 1; off < 64; off <<= 1) {
        int y = __shfl_up(inc, off);
        if (lane >= off) inc += y;
    }
    if (lane == 63) s_wt[wid] = inc;
    __syncthreads();   // B1
    const int w0 = s_wt[0], w1 = s_wt[1], w2 = s_wt[2], w3 = s_wt[3];
    const int total = w0 + w1 + w2 + w3;
    const bool ovf = (s_wc[0] > SEGG) | (s_wc[1] > SEGG) |
                     (s_wc[2] > SEGG) | (s_wc[3] > SEGG);
    const int wbase = (wid > 0 ? w0 : 0) + (wid > 1 ? w1 : 0) + (wid > 2 ? w2 : 0);
    const int myoff = wbase + inc - cnt;

    // ---- extraction write: re-read my groups, emit keys sequentially ----
    {
        int c = 0;
        for (int g = 0; g < 3; ++g) {
            const int gi = g * 64 + lane;
            if (gi < cwg) {
                const float4 v = wseg[gi];
                const float e[4] = {v.x, v.y, v.z, v.w};
#pragma unroll
                for (int q = 0; q < 4; ++q) {
                    if (e[q] >= THRESH) {
                        const int d = myoff + c;
                        if (d < CAP) s_cand[d] = f2key(e[q]);
                        ++c;
                    }
                }
            }
        }
    }
    __syncthreads();   // B2  (s_seg dead from here; hist aliases it)

    // ---- remove one instance of the positive ----
    const float pos = rowp[target];
    const uint32_t tkey = f2key(pos);
    const int tclamp = min(total, CAP);
    if (pos >= THRESH) {
        for (int i = t; i < tclamp; i += BLOCK)
            if (s_cand[i] == tkey) { atomicCAS(&s_found, -1, i); break; }
    }
    __syncthreads();   // B3
    int ncand = total;
    if (s_found >= 0) {
        ncand = total - 1;
        if (t == 0) s_cand[s_found] = s_cand[ncand];
    }
    __syncthreads();   // B4

    const bool fast = !ovf && (total <= CAP) && (ncand >= K_HARD);
    bool needfb = !fast;
    float local = 0.0f;
    uint32_t* hist = (uint32_t*)s_seg;

    if (fast) {
        for (int i = t; i < NB; i += BLOCK) hist[i] = 0;
        __syncthreads();   // B5
        for (int i = t; i < ncand; i += BLOCK)
            atomicAdd(&hist[min((s_cand[i] - KEY_MIN) >> 14, (uint32_t)(NB - 1))], 1u);
        __syncthreads();   // B6

        // shfl suffix scan to find pivot bin
        const int base4 = t * 4;
        const int c0 = (int)hist[base4], c1 = (int)hist[base4 + 1],
                  c2 = (int)hist[base4 + 2], c3 = (int)hist[base4 + 3];
        const int own = c0 + c1 + c2 + c3;
        int suf = own;
        for (int off = 1; off < 64; off <<= 1) {
            int y = __shfl_down(suf, off);
            if (lane + off < 64) suf += y;
        }
        if (lane == 0) s_wt[wid] = suf;
        if (t == 0) s_nsmall = 0;
        __syncthreads();   // B7
        int wsuf = 0;
        for (int w = wid + 1; w < 4; ++w) wsuf += s_wt[w];
        int run = wsuf + (suf - own);
        {
            const int cs[4] = {c0, c1, c2, c3};
            for (int b = 3; b >= 0; --b) {
                const int cc = cs[b];
                if (run < K_HARD && run + cc >= K_HARD) {
                    s_pivot = base4 + b; s_krem = K_HARD - run;
                }
                run += cc;
            }
        }
        __syncthreads();   // B8
        const uint32_t B = (uint32_t)s_pivot;
        const int krem = s_krem;

        for (int i = t; i < ncand; i += BLOCK) {
            const uint32_t k = s_cand[i];
            const uint32_t kb = min((k - KEY_MIN) >> 14, (uint32_t)(NB - 1));
            if (kb > B) local += softplus_f(key2f(k));
            else if (kb == B) {
                const int d = atomicAdd(&s_nsmall, 1);
                if (d < SMALL) { s_skey[d] = k; s_sidx[d] = i; }
            }
        }
        __syncthreads();   // B9
        const int m = s_nsmall;
        if (m > SMALL) { needfb = true; local = 0.0f; }
        else {
            for (int i = t; i < m; i += BLOCK) {
                const uint32_t ki = s_skey[i]; const int ii = s_sidx[i];
                int r = 0;
                for (int j = 0; j < m; ++j) {
                    const uint32_t kj = s_skey[j];
                    r += (kj > ki) || (kj == ki && s_sidx[j] < ii);
                }
                if (r < krem) local += softplus_f(key2f(ki));
            }
        }
    }

    if (needfb) {
        // ---- generic exact fallback: 10+10+10+2 radix from global ----
        local = 0.0f;
        int* part = (int*)s_cand;
        for (int i = t; i < NB; i += BLOCK) hist[i] = 0;
        __syncthreads();
        for (int j = t; j < N_COLS; j += BLOCK) {
            if (j == target) continue;
            atomicAdd(&hist[f2key(rowp[j]) >> 22], 1u);
        }
        __syncthreads();
        pivot_scan(hist, K_HARD, part, &s_pivot, &s_krem);
        const int p1 = s_pivot, k1r = s_krem;

        for (int i = t; i < NB; i += BLOCK) hist[i] = 0;
        __syncthreads();
        for (int j = t; j < N_COLS; j += BLOCK) {
            if (j == target) continue;
            const uint32_t k = f2key(rowp[j]);
            if ((int)(k >> 22) == p1) atomicAdd(&hist[(k >> 12) & 1023u], 1u);
        }
        __syncthreads();
        pivot_scan(hist, k1r, part, &s_pivot, &s_krem);
        const uint32_t pref2 = ((uint32_t)p1 << 10) | (uint32_t)s_pivot;
        const int k2r = s_krem;

        for (int i = t; i < NB; i += BLOCK) hist[i] = 0;
        __syncthreads();
        for (int j = t; j < N_COLS; j += BLOCK) {
            if (j == target) continue;
            const uint32_t k = f2key(rowp[j]);
            if ((k >> 12) == pref2) atomicAdd(&hist[(k >> 2) & 1023u], 1u);
        }
        __syncthreads();
        pivot_scan(hist, k2r, part, &s_pivot, &s_krem);
        const uint32_t pref3 = (pref2 << 10) | (uint32_t)s_pivot;
        const int k3r = s_krem;

        for (int i = t; i < 4; i += BLOCK) hist[i] = 0;
        __syncthreads();
        for (int j = t; j < N_COLS; j += BLOCK) {
            if (j == target) continue;
            const uint32_t k = f2key(rowp[j]);
            if ((k >> 2) == pref3) atomicAdd(&hist[k & 3u], 1u);
        }
        __syncthreads();
        if (t == 0) {
            int running = 0;
            for (int b = 3; b >= 0; --b) {
                const int cc = (int)hist[b];
                if (running < k3r && running + cc >= k3r) {
                    s_pivot = b; s_krem = k3r - running;
                }
                running += cc;
            }
        }
        __syncthreads();
        const uint32_t T = (pref3 << 2) | (uint32_t)s_pivot;
        const int tie = s_krem;

        for (int j = t; j < N_COLS; j += BLOCK) {
            if (j == target) continue;
            const uint32_t k = f2key(rowp[j]);
            if (k > T) local += softplus_f(key2f(k));
        }
        if (t == 0) local += (float)tie * softplus_f(key2f(T));
    }

    // ---- block reduce + plain store (NO global atomic) ----
    for (int off = 32; off > 0; off >>= 1) local += __shfl_down(local, off);
    if (lane == 0) s_fw[wid] = local;
    __syncthreads();
    if (t == 0) {
        const float tot = s_fw[0] + s_fw[1] + s_fw[2] + s_fw[3];
        const float l_neg = tot / (float)K_HARD;
        const float l_pos = softplus_f(-pos);
        partial[row] = DELTA_W * l_pos + l_neg;
    }
}

__global__ __launch_bounds__(BLOCK) void mmcl_reduce(
        const float* __restrict__ partial, float* __restrict__ out) {
    __shared__ float s_fw[4];
    const int t = threadIdx.x;
    float local = 0.0f;
    for (int i = t; i < M_ROWS; i += BLOCK) local += partial[i];
    for (int off = 32; off > 0; off >>= 1) local += __shfl_down(local, off);
    if ((t & 63) == 0) s_fw[t >> 6] = local;
    __syncthreads();
    if (t == 0)
        out[0] = (s_fw[0] + s_fw[1] + s_fw[2] + s_fw[3]) * (1.0f / (float)M_ROWS);
}

extern "C" void kernel_launch(void* const* d_in, const int* in_sizes, int n_in,
                              void* d_out, int out_size, void* d_ws, size_t ws_size,
                              hipStream_t stream) {
    const float* inputs = (const float*)d_in[0];
    const int* targets = (const int*)d_in[1];
    float* out = (float*)d_out;
    float* partial = (float*)d_ws;   // 16 KB, fully overwritten every launch
    mmcl_main<<<M_ROWS, BLOCK, 0, stream>>>(inputs, targets, partial);
    mmcl_reduce<<<1, BLOCK, 0, stream>>>(partial, out);
}